// Round 1
// baseline (327.260 us; speedup 1.0000x reference)
//
#include <hip/hip_runtime.h>
#include <hip/hip_bf16.h>
#include <hip/hip_fp16.h>

// Problem constants (from reference setup_inputs)
#define N0 200000
#define N1 50000
#define N2 10000
#define E1C 800000
#define E2C 160000
// IN_F=128, HID=128, RANK=64, OUT_C=64
// Bucket geometry: 64 dsts per bucket.
#define NB1 784      // ceil(50000/64)=782, padded to mult of 8 (98/partition)
#define NB2 160      // ceil(10000/64)=157, padded to mult of 8 (20/partition)
#define NBT (NB1 + NB2)          // 944 global buckets
#define CH1 64       // layer-1 edge chunks in hist/scatter
#define CH2 16       // layer-2 edge chunks
#define NT1 3125     // N1/16 row-tiles
#define NT2 625      // N2/16 row-tiles

struct H4 { __half2 a, b; };              // 8 B
struct H8 { __half2 a, b, c, d; };        // 16 B

typedef _Float16 f16x8 __attribute__((ext_vector_type(8)));
typedef float f32x4 __attribute__((ext_vector_type(4)));
#define MFMA16(a, b, c) __builtin_amdgcn_mfma_f32_16x16x32_f16(a, b, c, 0, 0, 0)

// Transposed fp16 weight block offsets (in halves):
// Wsrc1t[64][128] @0, Wdst1t[64][128] @8192, Wout1t[128][64] @16384,
// Wsrc2t[64][128] @24576, Wdst2t[64][128] @32768, Wout2t[64][64] @40960
#define WT_TOTAL 45056

// ---------------------------------------------------------------------------
// prep: zero hist[NBT], convert x->fp16, transpose all W to fp16 Wt[n][k].
__global__ __launch_bounds__(256) void prep(int4* __restrict__ histz,
                                            const float4* __restrict__ x4,
                                            H4* __restrict__ xh4,
                                            const float* __restrict__ Wsrc1,
                                            const float* __restrict__ Wdst1,
                                            const float* __restrict__ Wout1,
                                            const float* __restrict__ Wsrc2,
                                            const float* __restrict__ Wdst2,
                                            const float* __restrict__ Wout2,
                                            __half* __restrict__ wt) {
    const int NZ4 = NBT / 4;               // 236 int4
    const int NC = N0 * 128 / 4;           // 6.4M float4
    int i = blockIdx.x * 256 + threadIdx.x;
    if (i < NZ4) {
        histz[i] = make_int4(0, 0, 0, 0);
    } else {
        int j = i - NZ4;
        if (j < NC) {
            float4 v = x4[j];
            H4 o;
            o.a = __floats2half2_rn(v.x, v.y);
            o.b = __floats2half2_rn(v.z, v.w);
            xh4[j] = o;
        } else {
            int e = j - NC;
            if (e < WT_TOTAL) {
                float v;
                if (e < 8192)       { int e2 = e;         int n = e2 >> 7, k = e2 & 127; v = Wsrc1[k * 64 + n]; }
                else if (e < 16384) { int e2 = e - 8192;  int n = e2 >> 7, k = e2 & 127; v = Wdst1[k * 64 + n]; }
                else if (e < 24576) { int e2 = e - 16384; int n = e2 >> 6, k = e2 & 63;  v = Wout1[k * 128 + n]; }
                else if (e < 32768) { int e2 = e - 24576; int n = e2 >> 7, k = e2 & 127; v = Wsrc2[k * 64 + n]; }
                else if (e < 40960) { int e2 = e - 32768; int n = e2 >> 7, k = e2 & 127; v = Wdst2[k * 64 + n]; }
                else                { int e2 = e - 40960; int n = e2 >> 6, k = e2 & 63;  v = Wout2[k * 64 + n]; }
                wt[e] = __float2half(v);
            }
        }
    }
}

// ---------------------------------------------------------------------------
// Per-bucket histogram, both layers (LDS histogram, one global add per bucket).
__global__ __launch_bounds__(256) void hist_k(const int* __restrict__ dst1,
                                              const int* __restrict__ dst2,
                                              int* __restrict__ hist) {
    __shared__ int hl[NB1];
    int b = blockIdx.x;
    const int* dst; int nb, goff, e0, e1;
    if (b < CH1) {
        dst = dst1; nb = NB1; goff = 0;
        int per = E1C / CH1 / 4;
        e0 = b * per; e1 = e0 + per;
    } else {
        dst = dst2; nb = NB2; goff = NB1;
        int per = E2C / CH2 / 4;
        int c = b - CH1;
        e0 = c * per; e1 = e0 + per;
    }
    for (int i = threadIdx.x; i < nb; i += 256) hl[i] = 0;
    __syncthreads();
    const int4* d4 = reinterpret_cast<const int4*>(dst);
    for (int i = e0 + threadIdx.x; i < e1; i += 256) {
        int4 v = d4[i];
        atomicAdd(&hl[v.x >> 6], 1);
        atomicAdd(&hl[v.y >> 6], 1);
        atomicAdd(&hl[v.z >> 6], 1);
        atomicAdd(&hl[v.w >> 6], 1);
    }
    __syncthreads();
    for (int i = threadIdx.x; i < nb; i += 256) {
        int c = hl[i];
        if (c) atomicAdd(&hist[goff + i], c);
    }
}

// ---------------------------------------------------------------------------
// Single-block exclusive scan of hist[NBT] -> base[] and cursor[].
__global__ __launch_bounds__(1024) void scan_small(const int* __restrict__ hist,
                                                   int* __restrict__ base,
                                                   int* __restrict__ cursor) {
    int t = threadIdx.x, lane = t & 63, wid = t >> 6;
    int v = (t < NBT) ? hist[t] : 0;
    int s = v;
    #pragma unroll
    for (int o = 1; o < 64; o <<= 1) { int u = __shfl_up(s, o, 64); if (lane >= o) s += u; }
    __shared__ int ws[16];
    if (lane == 63) ws[wid] = s;
    __syncthreads();
    if (wid == 0 && lane < 16) {
        int w = ws[lane];
        #pragma unroll
        for (int o = 1; o < 16; o <<= 1) { int u = __shfl_up(w, o, 64); if (lane >= o) w += u; }
        ws[lane] = w;
    }
    __syncthreads();
    int excl = ((wid == 0) ? 0 : ws[wid - 1]) + (s - v);
    if (t < NBT) { base[t] = excl; cursor[t] = excl; }
}

// ---------------------------------------------------------------------------
// Bucket scatter: block = (partition, chunk); LDS counts, one global
// reservation per bucket, packed coalesced edge writes (src<<6 | dst&63).
__global__ __launch_bounds__(256) void scatter_k(const int* __restrict__ dst1,
                                                 const int* __restrict__ src1,
                                                 const int* __restrict__ dst2,
                                                 const int* __restrict__ src2,
                                                 int* __restrict__ cursor,
                                                 int* __restrict__ edgebuf) {
    __shared__ int cnt_l[98];
    __shared__ int rsv[98];
    __shared__ int cur_l[98];
    int b = blockIdx.x;
    const int* dst; const int* srcp; int goff, bpp, lo, e0, e1;
    if (b < 8 * CH1) {
        dst = dst1; srcp = src1; goff = 0; bpp = NB1 / 8;
        int part = b & 7, chunk = b >> 3;
        lo = part * bpp;
        int per = E1C / CH1 / 4;
        e0 = chunk * per; e1 = e0 + per;
    } else {
        int k = b - 8 * CH1;
        dst = dst2; srcp = src2; goff = NB1; bpp = NB2 / 8;
        int part = k & 7, chunk = k >> 3;
        lo = part * bpp;
        int per = E2C / CH2 / 4;
        e0 = chunk * per; e1 = e0 + per;
    }
    for (int i = threadIdx.x; i < bpp; i += 256) cnt_l[i] = 0;
    __syncthreads();
    const int4* d4 = reinterpret_cast<const int4*>(dst);
    const int4* s4 = reinterpret_cast<const int4*>(srcp);
    for (int i = e0 + threadIdx.x; i < e1; i += 256) {
        int4 v = d4[i];
        int b0 = (v.x >> 6) - lo; if ((unsigned)b0 < (unsigned)bpp) atomicAdd(&cnt_l[b0], 1);
        int b1 = (v.y >> 6) - lo; if ((unsigned)b1 < (unsigned)bpp) atomicAdd(&cnt_l[b1], 1);
        int b2 = (v.z >> 6) - lo; if ((unsigned)b2 < (unsigned)bpp) atomicAdd(&cnt_l[b2], 1);
        int b3 = (v.w >> 6) - lo; if ((unsigned)b3 < (unsigned)bpp) atomicAdd(&cnt_l[b3], 1);
    }
    __syncthreads();
    for (int i = threadIdx.x; i < bpp; i += 256) {
        int c = cnt_l[i];
        rsv[i] = c ? atomicAdd(&cursor[goff + lo + i], c) : 0;
        cur_l[i] = 0;
    }
    __syncthreads();
    for (int i = e0 + threadIdx.x; i < e1; i += 256) {
        int4 dv = d4[i];
        int4 sv = s4[i];
        int b0 = (dv.x >> 6) - lo;
        if ((unsigned)b0 < (unsigned)bpp) {
            int p = atomicAdd(&cur_l[b0], 1);
            edgebuf[rsv[b0] + p] = (sv.x << 6) | (dv.x & 63);
        }
        int b1 = (dv.y >> 6) - lo;
        if ((unsigned)b1 < (unsigned)bpp) {
            int p = atomicAdd(&cur_l[b1], 1);
            edgebuf[rsv[b1] + p] = (sv.y << 6) | (dv.y & 63);
        }
        int b2 = (dv.z >> 6) - lo;
        if ((unsigned)b2 < (unsigned)bpp) {
            int p = atomicAdd(&cur_l[b2], 1);
            edgebuf[rsv[b2] + p] = (sv.z << 6) | (dv.z & 63);
        }
        int b3 = (dv.w >> 6) - lo;
        if ((unsigned)b3 < (unsigned)bpp) {
            int p = atomicAdd(&cur_l[b3], 1);
            edgebuf[rsv[b3] + p] = (sv.w << 6) | (dv.w & 63);
        }
    }
}

// ---------------------------------------------------------------------------
// Bucket segment-mean: block = bucket (64 dsts). LDS ELL from contiguous
// edge slice, wave-per-dst fp16 gather, fp32 accumulate, fp16 output rows.
__global__ __launch_bounds__(256) void seg_mean_b(const __half* __restrict__ X,
                                                  const int* __restrict__ edgebuf,
                                                  const int* __restrict__ base,
                                                  const int* __restrict__ hist,
                                                  __half* __restrict__ aggh,
                                                  int ndst, int gb0) {
    __shared__ int cnt_lds[64];
    __shared__ int ell[64 * 64];
    int bkt = blockIdx.x;
    int gb = gb0 + bkt;
    int ebase = base[gb];
    int ecnt = hist[gb];
    if (threadIdx.x < 64) cnt_lds[threadIdx.x] = 0;
    __syncthreads();
    for (int i = threadIdx.x; i < ecnt; i += 256) {
        int v = edgebuf[ebase + i];
        int ld = v & 63;
        int p = atomicAdd(&cnt_lds[ld], 1);
        if (p < 64) ell[(ld << 6) + p] = v >> 6;
    }
    __syncthreads();
    int wid = threadIdx.x >> 6, lane = threadIdx.x & 63;
    int sub = lane >> 4, fq = lane & 15;
    const H8* Xr = reinterpret_cast<const H8*>(X);
    for (int ld = wid; ld < 64; ld += 4) {
        int d = (bkt << 6) + ld;
        if (d >= ndst) continue;           // wave-uniform
        int cn = cnt_lds[ld];
        int m = cn < 64 ? cn : 64;
        float acc[8];
        #pragma unroll
        for (int i = 0; i < 8; ++i) acc[i] = 0.0f;
        for (int e = sub; e < m; e += 4) {
            int sidx = ell[(ld << 6) + e];
            H8 p = Xr[(size_t)sidx * 16 + fq];
            float2 f0 = __half22float2(p.a);
            float2 f1 = __half22float2(p.b);
            float2 f2 = __half22float2(p.c);
            float2 f3 = __half22float2(p.d);
            acc[0] += f0.x; acc[1] += f0.y; acc[2] += f1.x; acc[3] += f1.y;
            acc[4] += f2.x; acc[5] += f2.y; acc[6] += f3.x; acc[7] += f3.y;
        }
        #pragma unroll
        for (int o = 16; o <= 32; o <<= 1) {
            #pragma unroll
            for (int i = 0; i < 8; ++i) acc[i] += __shfl_xor(acc[i], o, 64);
        }
        if (sub == 0) {
            float inv = (cn > 0) ? (1.0f / (float)cn) : 0.0f;
            H8 o;
            o.a = __floats2half2_rn(acc[0] * inv, acc[1] * inv);
            o.b = __floats2half2_rn(acc[2] * inv, acc[3] * inv);
            o.c = __floats2half2_rn(acc[4] * inv, acc[5] * inv);
            o.d = __floats2half2_rn(acc[6] * inv, acc[7] * inv);
            *reinterpret_cast<H8*>(aggh + (size_t)d * 128 + fq * 8) = o;
        }
    }
}

// ---------------------------------------------------------------------------
// Layer 1, fully fused MFMA: hh = fp16(relu(((aggh@Wsrc1)*(xh@Wdst1))@Wout1 + b1))
// One wave per 16-row tile. A-frags direct global 16B loads; B-frags from
// L1-hot transposed Wt[n][k]; z tile round-trips C-layout->A-layout via
// per-wave LDS (16 x 72 halves, pad keeps b128 reads 2-way/free).
__global__ __launch_bounds__(256) void layer1_mfma(const __half* __restrict__ aggh,
                                                   const __half* __restrict__ xh,
                                                   const __half* __restrict__ wth,
                                                   const float* __restrict__ b1,
                                                   __half* __restrict__ hh) {
    __shared__ _Float16 zt[4][16][72];
    int wave = threadIdx.x >> 6, lane = threadIdx.x & 63;
    int tile = blockIdx.x * 4 + wave;
    if (tile >= NT1) return;
    int r0 = tile * 16;
    int m = lane & 15, q = lane >> 4;
    const _Float16* A1 = (const _Float16*)aggh + (size_t)(r0 + m) * 128 + q * 8;
    const _Float16* A2 = (const _Float16*)xh   + (size_t)(r0 + m) * 128 + q * 8;
    const _Float16* wt = (const _Float16*)wth;
    const _Float16* Wsrc = wt;               // [64][128]
    const _Float16* Wdst = wt + 8192;        // [64][128]
    const _Float16* Wout = wt + 16384;       // [128][64]

    f32x4 accA[4], accB[4];
    #pragma unroll
    for (int nt = 0; nt < 4; ++nt) { accA[nt] = (f32x4)(0.0f); accB[nt] = (f32x4)(0.0f); }
    #pragma unroll
    for (int kc = 0; kc < 4; ++kc) {
        f16x8 a1 = *(const f16x8*)(A1 + kc * 32);
        f16x8 a2 = *(const f16x8*)(A2 + kc * 32);
        #pragma unroll
        for (int nt = 0; nt < 4; ++nt) {
            f16x8 ba = *(const f16x8*)(Wsrc + (nt * 16 + m) * 128 + kc * 32 + q * 8);
            f16x8 bb = *(const f16x8*)(Wdst + (nt * 16 + m) * 128 + kc * 32 + q * 8);
            accA[nt] = MFMA16(a1, ba, accA[nt]);
            accB[nt] = MFMA16(a2, bb, accB[nt]);
        }
    }
    // z = accA*accB, C-layout (row=q*4+i, col=nt*16+m) -> LDS A-layout staging
    #pragma unroll
    for (int nt = 0; nt < 4; ++nt)
        #pragma unroll
        for (int i = 0; i < 4; ++i)
            zt[wave][q * 4 + i][nt * 16 + m] = (_Float16)(accA[nt][i] * accB[nt][i]);
    // per-wave LDS ordering: DS ops from one wave complete in order; compiler
    // inserts lgkmcnt for the dependent reads below. No block barrier needed.
    f32x4 acc2[8];
    #pragma unroll
    for (int nt = 0; nt < 8; ++nt) acc2[nt] = (f32x4)(0.0f);
    #pragma unroll
    for (int kc = 0; kc < 2; ++kc) {
        f16x8 az = *(const f16x8*)(&zt[wave][m][kc * 32 + q * 8]);
        #pragma unroll
        for (int nt = 0; nt < 8; ++nt) {
            f16x8 bo = *(const f16x8*)(Wout + (nt * 16 + m) * 64 + kc * 32 + q * 8);
            acc2[nt] = MFMA16(az, bo, acc2[nt]);
        }
    }
    #pragma unroll
    for (int nt = 0; nt < 8; ++nt) {
        float bz = b1[nt * 16 + m];
        #pragma unroll
        for (int i = 0; i < 4; ++i) {
            float v = fmaxf(acc2[nt][i] + bz, 0.0f);
            hh[(size_t)(r0 + q * 4 + i) * 128 + nt * 16 + m] = __float2half(v);
        }
    }
}

// ---------------------------------------------------------------------------
// Layer 2, fully fused MFMA: out = ((agg2h@Wsrc2)*(hh@Wdst2))@Wout2 + b2
__global__ __launch_bounds__(256) void layer2_mfma(const __half* __restrict__ aggh,
                                                   const __half* __restrict__ hh,
                                                   const __half* __restrict__ wth,
                                                   const float* __restrict__ b2,
                                                   float* __restrict__ out) {
    __shared__ _Float16 zt[4][16][72];
    int wave = threadIdx.x >> 6, lane = threadIdx.x & 63;
    int tile = blockIdx.x * 4 + wave;
    if (tile >= NT2) return;
    int r0 = tile * 16;
    int m = lane & 15, q = lane >> 4;
    const _Float16* A1 = (const _Float16*)aggh + (size_t)(r0 + m) * 128 + q * 8;
    const _Float16* A2 = (const _Float16*)hh   + (size_t)(r0 + m) * 128 + q * 8;
    const _Float16* wt = (const _Float16*)wth;
    const _Float16* Wsrc = wt + 24576;       // [64][128]
    const _Float16* Wdst = wt + 32768;       // [64][128]
    const _Float16* Wout = wt + 40960;       // [64][64]

    f32x4 accA[4], accB[4];
    #pragma unroll
    for (int nt = 0; nt < 4; ++nt) { accA[nt] = (f32x4)(0.0f); accB[nt] = (f32x4)(0.0f); }
    #pragma unroll
    for (int kc = 0; kc < 4; ++kc) {
        f16x8 a1 = *(const f16x8*)(A1 + kc * 32);
        f16x8 a2 = *(const f16x8*)(A2 + kc * 32);
        #pragma unroll
        for (int nt = 0; nt < 4; ++nt) {
            f16x8 ba = *(const f16x8*)(Wsrc + (nt * 16 + m) * 128 + kc * 32 + q * 8);
            f16x8 bb = *(const f16x8*)(Wdst + (nt * 16 + m) * 128 + kc * 32 + q * 8);
            accA[nt] = MFMA16(a1, ba, accA[nt]);
            accB[nt] = MFMA16(a2, bb, accB[nt]);
        }
    }
    #pragma unroll
    for (int nt = 0; nt < 4; ++nt)
        #pragma unroll
        for (int i = 0; i < 4; ++i)
            zt[wave][q * 4 + i][nt * 16 + m] = (_Float16)(accA[nt][i] * accB[nt][i]);
    f32x4 acc2[4];
    #pragma unroll
    for (int nt = 0; nt < 4; ++nt) acc2[nt] = (f32x4)(0.0f);
    #pragma unroll
    for (int kc = 0; kc < 2; ++kc) {
        f16x8 az = *(const f16x8*)(&zt[wave][m][kc * 32 + q * 8]);
        #pragma unroll
        for (int nt = 0; nt < 4; ++nt) {
            f16x8 bo = *(const f16x8*)(Wout + (nt * 16 + m) * 64 + kc * 32 + q * 8);
            acc2[nt] = MFMA16(az, bo, acc2[nt]);
        }
    }
    #pragma unroll
    for (int nt = 0; nt < 4; ++nt) {
        float bz = b2[nt * 16 + m];
        #pragma unroll
        for (int i = 0; i < 4; ++i)
            out[(size_t)(r0 + q * 4 + i) * 64 + nt * 16 + m] = acc2[nt][i] + bz;
    }
}

// ---------------------------------------------------------------------------
extern "C" void kernel_launch(void* const* d_in, const int* in_sizes, int n_in,
                              void* d_out, int out_size, void* d_ws, size_t ws_size,
                              hipStream_t stream) {
    const float* x     = (const float*)d_in[0];
    const float* Wsrc1 = (const float*)d_in[1];
    const float* Wdst1 = (const float*)d_in[2];
    const float* Wout1 = (const float*)d_in[3];
    const float* b1    = (const float*)d_in[4];
    const float* Wsrc2 = (const float*)d_in[5];
    const float* Wdst2 = (const float*)d_in[6];
    const float* Wout2 = (const float*)d_in[7];
    const float* b2    = (const float*)d_in[8];
    const int* src1    = (const int*)d_in[9];
    const int* dst1    = (const int*)d_in[10];
    const int* src2    = (const int*)d_in[11];
    const int* dst2    = (const int*)d_in[12];
    float* out = (float*)d_out;

    // workspace layout (byte offsets, all 16B-aligned)
    char* basep = (char*)d_ws;
    __half* xh    = (__half*)(basep);                  // 51.2 MB  [N0][128]
    __half* agg1h = (__half*)(basep + 51200000);       // 12.8 MB  [N1][128]
    __half* hh    = (__half*)(basep + 64000000);       // 12.8 MB  [N1][128]
    __half* agg2h = (__half*)(basep + 76800000);       // 2.56 MB  [N2][128]
    int* hist    = (int*)(basep + 79360000);           // NBT
    int* bbase   = hist + NBT;
    int* cursor  = bbase + NBT;
    int* edgebuf = cursor + NBT;                       // 960000 ints
    __half* wt   = (__half*)(basep + 83211328);        // 90 KB transposed weights

    // --- prep (zero hist + x->fp16 + W->fp16 transposed) ---
    {
        int total = NBT / 4 + N0 * 128 / 4 + WT_TOTAL;
        prep<<<(total + 255) / 256, 256, 0, stream>>>((int4*)hist, (const float4*)x, (H4*)xh,
                                                      Wsrc1, Wdst1, Wout1, Wsrc2, Wdst2, Wout2, wt);
    }
    // --- bucket histogram -> scan -> coalesced bucket scatter ---
    hist_k<<<CH1 + CH2, 256, 0, stream>>>(dst1, dst2, hist);
    scan_small<<<1, 1024, 0, stream>>>(hist, bbase, cursor);
    scatter_k<<<8 * CH1 + 8 * CH2, 256, 0, stream>>>(dst1, src1, dst2, src2, cursor, edgebuf);

    // --- layer 1 ---
    seg_mean_b<<<NB1, 256, 0, stream>>>(xh, edgebuf, bbase, hist, agg1h, N1, 0);
    layer1_mfma<<<(NT1 + 3) / 4, 256, 0, stream>>>(agg1h, xh, wt, b1, hh);

    // --- layer 2 ---
    seg_mean_b<<<157, 256, 0, stream>>>(hh, edgebuf, bbase, hist, agg2h, N2, NB1);
    layer2_mfma<<<(NT2 + 3) / 4, 256, 0, stream>>>(agg2h, hh, wt, b2, out);
}

// Round 2
// 310.855 us; speedup vs baseline: 1.0528x; 1.0528x over previous
//
#include <hip/hip_runtime.h>
#include <hip/hip_bf16.h>
#include <hip/hip_fp16.h>

// Problem constants
#define N0 200000
#define N1 50000
#define N2 10000
#define E1C 800000
#define E2C 160000
// IN_F=128, HID=128, RANK=64, OUT_C=64
#define NB1 784      // ceil(50000/64)=782, padded to mult of 8
#define NB2 160      // ceil(10000/64)=157, padded to mult of 8
#define NBT (NB1 + NB2)
#define CH1 64
#define CH2 16
#define NTP 12500    // N0/16 projection tiles
#define NT1 3125     // N1/16
#define NT2 625      // N2/16

struct H8 { __half2 a, b, c, d; };        // 16 B

typedef _Float16 f16x8 __attribute__((ext_vector_type(8)));
typedef float f32x4 __attribute__((ext_vector_type(4)));
#define MFMA16(a, b, c) __builtin_amdgcn_mfma_f32_16x16x32_f16(a, b, c, 0, 0, 0)

// Transposed fp16 weight block offsets (halves):
// Wsrc1t[64][128]@0, Wdst1t[64][128]@8192, Wout1t[128][64]@16384,
// Wsrc2t[64][128]@24576, Wdst2t[64][128]@32768, Wout2t[64][64]@40960
#define WT_TOTAL 45056

// ---------------------------------------------------------------------------
// prep_small: zero hist[NBT] + transpose all W to fp16 Wt[n][k]. Tiny.
__global__ __launch_bounds__(256) void prep_small(int4* __restrict__ histz,
                                                  const float* __restrict__ Wsrc1,
                                                  const float* __restrict__ Wdst1,
                                                  const float* __restrict__ Wout1,
                                                  const float* __restrict__ Wsrc2,
                                                  const float* __restrict__ Wdst2,
                                                  const float* __restrict__ Wout2,
                                                  __half* __restrict__ wt) {
    const int NZ4 = NBT / 4;               // 236 int4
    int i = blockIdx.x * 256 + threadIdx.x;
    if (i < NZ4) {
        histz[i] = make_int4(0, 0, 0, 0);
    } else {
        int e = i - NZ4;
        if (e < WT_TOTAL) {
            float v;
            if (e < 8192)       { int e2 = e;         int n = e2 >> 7, k = e2 & 127; v = Wsrc1[k * 64 + n]; }
            else if (e < 16384) { int e2 = e - 8192;  int n = e2 >> 7, k = e2 & 127; v = Wdst1[k * 64 + n]; }
            else if (e < 24576) { int e2 = e - 16384; int n = e2 >> 6, k = e2 & 63;  v = Wout1[k * 128 + n]; }
            else if (e < 32768) { int e2 = e - 24576; int n = e2 >> 7, k = e2 & 127; v = Wsrc2[k * 64 + n]; }
            else if (e < 40960) { int e2 = e - 32768; int n = e2 >> 7, k = e2 & 127; v = Wdst2[k * 64 + n]; }
            else                { int e2 = e - 40960; int n = e2 >> 6, k = e2 & 63;  v = Wout2[k * 64 + n]; }
            wt[e] = __float2half(v);
        }
    }
}

// ---------------------------------------------------------------------------
// Per-bucket histogram, both layers.
__global__ __launch_bounds__(256) void hist_k(const int* __restrict__ dst1,
                                              const int* __restrict__ dst2,
                                              int* __restrict__ hist) {
    __shared__ int hl[NB1];
    int b = blockIdx.x;
    const int* dst; int nb, goff, e0, e1;
    if (b < CH1) {
        dst = dst1; nb = NB1; goff = 0;
        int per = E1C / CH1 / 4;
        e0 = b * per; e1 = e0 + per;
    } else {
        dst = dst2; nb = NB2; goff = NB1;
        int per = E2C / CH2 / 4;
        int c = b - CH1;
        e0 = c * per; e1 = e0 + per;
    }
    for (int i = threadIdx.x; i < nb; i += 256) hl[i] = 0;
    __syncthreads();
    const int4* d4 = reinterpret_cast<const int4*>(dst);
    for (int i = e0 + threadIdx.x; i < e1; i += 256) {
        int4 v = d4[i];
        atomicAdd(&hl[v.x >> 6], 1);
        atomicAdd(&hl[v.y >> 6], 1);
        atomicAdd(&hl[v.z >> 6], 1);
        atomicAdd(&hl[v.w >> 6], 1);
    }
    __syncthreads();
    for (int i = threadIdx.x; i < nb; i += 256) {
        int c = hl[i];
        if (c) atomicAdd(&hist[goff + i], c);
    }
}

// ---------------------------------------------------------------------------
// Single-block exclusive scan of hist[NBT] -> base[] and cursor[].
__global__ __launch_bounds__(1024) void scan_small(const int* __restrict__ hist,
                                                   int* __restrict__ base,
                                                   int* __restrict__ cursor) {
    int t = threadIdx.x, lane = t & 63, wid = t >> 6;
    int v = (t < NBT) ? hist[t] : 0;
    int s = v;
    #pragma unroll
    for (int o = 1; o < 64; o <<= 1) { int u = __shfl_up(s, o, 64); if (lane >= o) s += u; }
    __shared__ int ws[16];
    if (lane == 63) ws[wid] = s;
    __syncthreads();
    if (wid == 0 && lane < 16) {
        int w = ws[lane];
        #pragma unroll
        for (int o = 1; o < 16; o <<= 1) { int u = __shfl_up(w, o, 64); if (lane >= o) w += u; }
        ws[lane] = w;
    }
    __syncthreads();
    int excl = ((wid == 0) ? 0 : ws[wid - 1]) + (s - v);
    if (t < NBT) { base[t] = excl; cursor[t] = excl; }
}

// ---------------------------------------------------------------------------
// Bucket scatter (unchanged): packed coalesced edge writes (src<<6 | dst&63).
__global__ __launch_bounds__(256) void scatter_k(const int* __restrict__ dst1,
                                                 const int* __restrict__ src1,
                                                 const int* __restrict__ dst2,
                                                 const int* __restrict__ src2,
                                                 int* __restrict__ cursor,
                                                 int* __restrict__ edgebuf) {
    __shared__ int cnt_l[98];
    __shared__ int rsv[98];
    __shared__ int cur_l[98];
    int b = blockIdx.x;
    const int* dst; const int* srcp; int goff, bpp, lo, e0, e1;
    if (b < 8 * CH1) {
        dst = dst1; srcp = src1; goff = 0; bpp = NB1 / 8;
        int part = b & 7, chunk = b >> 3;
        lo = part * bpp;
        int per = E1C / CH1 / 4;
        e0 = chunk * per; e1 = e0 + per;
    } else {
        int k = b - 8 * CH1;
        dst = dst2; srcp = src2; goff = NB1; bpp = NB2 / 8;
        int part = k & 7, chunk = k >> 3;
        lo = part * bpp;
        int per = E2C / CH2 / 4;
        e0 = chunk * per; e1 = e0 + per;
    }
    for (int i = threadIdx.x; i < bpp; i += 256) cnt_l[i] = 0;
    __syncthreads();
    const int4* d4 = reinterpret_cast<const int4*>(dst);
    const int4* s4 = reinterpret_cast<const int4*>(srcp);
    for (int i = e0 + threadIdx.x; i < e1; i += 256) {
        int4 v = d4[i];
        int b0 = (v.x >> 6) - lo; if ((unsigned)b0 < (unsigned)bpp) atomicAdd(&cnt_l[b0], 1);
        int b1 = (v.y >> 6) - lo; if ((unsigned)b1 < (unsigned)bpp) atomicAdd(&cnt_l[b1], 1);
        int b2 = (v.z >> 6) - lo; if ((unsigned)b2 < (unsigned)bpp) atomicAdd(&cnt_l[b2], 1);
        int b3 = (v.w >> 6) - lo; if ((unsigned)b3 < (unsigned)bpp) atomicAdd(&cnt_l[b3], 1);
    }
    __syncthreads();
    for (int i = threadIdx.x; i < bpp; i += 256) {
        int c = cnt_l[i];
        rsv[i] = c ? atomicAdd(&cursor[goff + lo + i], c) : 0;
        cur_l[i] = 0;
    }
    __syncthreads();
    for (int i = e0 + threadIdx.x; i < e1; i += 256) {
        int4 dv = d4[i];
        int4 sv = s4[i];
        int b0 = (dv.x >> 6) - lo;
        if ((unsigned)b0 < (unsigned)bpp) {
            int p = atomicAdd(&cur_l[b0], 1);
            edgebuf[rsv[b0] + p] = (sv.x << 6) | (dv.x & 63);
        }
        int b1 = (dv.y >> 6) - lo;
        if ((unsigned)b1 < (unsigned)bpp) {
            int p = atomicAdd(&cur_l[b1], 1);
            edgebuf[rsv[b1] + p] = (sv.y << 6) | (dv.y & 63);
        }
        int b2 = (dv.z >> 6) - lo;
        if ((unsigned)b2 < (unsigned)bpp) {
            int p = atomicAdd(&cur_l[b2], 1);
            edgebuf[rsv[b2] + p] = (sv.z << 6) | (dv.z & 63);
        }
        int b3 = (dv.w >> 6) - lo;
        if ((unsigned)b3 < (unsigned)bpp) {
            int p = atomicAdd(&cur_l[b3], 1);
            edgebuf[rsv[b3] + p] = (sv.w << 6) | (dv.w & 63);
        }
    }
}

// ---------------------------------------------------------------------------
// proj1: h_src1 = fp16(x @ Wsrc1) for all N0 rows; h_dst1 = fp16(x @ Wdst1)
// for rows < N1. One wave per 16-row tile; A from f32 global (convert in reg),
// B from L1-hot transposed weights; C-layout fp16 scalar stores.
__global__ __launch_bounds__(256) void proj1(const float* __restrict__ x,
                                             const __half* __restrict__ wth,
                                             __half* __restrict__ hsrc,
                                             __half* __restrict__ hdst) {
    int wave = threadIdx.x >> 6, lane = threadIdx.x & 63;
    int tile = blockIdx.x * 4 + wave;
    if (tile >= NTP) return;
    int r0 = tile * 16;
    int m = lane & 15, q = lane >> 4;
    const float* A = x + (size_t)(r0 + m) * 128 + q * 8;
    const _Float16* wt = (const _Float16*)wth;
    const _Float16* Wsrc = wt;               // [64][128]
    const _Float16* Wdst = wt + 8192;        // [64][128]

    f16x8 a[4];
    #pragma unroll
    for (int kc = 0; kc < 4; ++kc) {
        float4 v0 = *(const float4*)(A + kc * 32);
        float4 v1 = *(const float4*)(A + kc * 32 + 4);
        f16x8 t;
        t[0] = (_Float16)v0.x; t[1] = (_Float16)v0.y; t[2] = (_Float16)v0.z; t[3] = (_Float16)v0.w;
        t[4] = (_Float16)v1.x; t[5] = (_Float16)v1.y; t[6] = (_Float16)v1.z; t[7] = (_Float16)v1.w;
        a[kc] = t;
    }
    f32x4 accS[4];
    #pragma unroll
    for (int nt = 0; nt < 4; ++nt) accS[nt] = (f32x4)(0.0f);
    #pragma unroll
    for (int kc = 0; kc < 4; ++kc)
        #pragma unroll
        for (int nt = 0; nt < 4; ++nt) {
            f16x8 b = *(const f16x8*)(Wsrc + (nt * 16 + m) * 128 + kc * 32 + q * 8);
            accS[nt] = MFMA16(a[kc], b, accS[nt]);
        }
    #pragma unroll
    for (int nt = 0; nt < 4; ++nt)
        #pragma unroll
        for (int i = 0; i < 4; ++i)
            hsrc[(size_t)(r0 + q * 4 + i) * 64 + nt * 16 + m] = __float2half(accS[nt][i]);

    if (tile < NT1) {                        // dst side only for rows < N1
        f32x4 accD[4];
        #pragma unroll
        for (int nt = 0; nt < 4; ++nt) accD[nt] = (f32x4)(0.0f);
        #pragma unroll
        for (int kc = 0; kc < 4; ++kc)
            #pragma unroll
            for (int nt = 0; nt < 4; ++nt) {
                f16x8 b = *(const f16x8*)(Wdst + (nt * 16 + m) * 128 + kc * 32 + q * 8);
                accD[nt] = MFMA16(a[kc], b, accD[nt]);
            }
        #pragma unroll
        for (int nt = 0; nt < 4; ++nt)
            #pragma unroll
            for (int i = 0; i < 4; ++i)
                hdst[(size_t)(r0 + q * 4 + i) * 64 + nt * 16 + m] = __float2half(accD[nt][i]);
    }
}

// ---------------------------------------------------------------------------
// Rank-64 bucket segment-mean: 128 B rows, 8-lane sub-groups -> <=8-deep
// dependent gather chain (avg 2). Same ELL build as before.
__global__ __launch_bounds__(256) void seg_mean64(const __half* __restrict__ X,
                                                  const int* __restrict__ edgebuf,
                                                  const int* __restrict__ base,
                                                  const int* __restrict__ hist,
                                                  __half* __restrict__ aggh,
                                                  int ndst, int gb0) {
    __shared__ int cnt_lds[64];
    __shared__ int ell[64 * 64];
    int bkt = blockIdx.x;
    int gb = gb0 + bkt;
    int ebase = base[gb];
    int ecnt = hist[gb];
    if (threadIdx.x < 64) cnt_lds[threadIdx.x] = 0;
    __syncthreads();
    for (int i = threadIdx.x; i < ecnt; i += 256) {
        int v = edgebuf[ebase + i];
        int ld = v & 63;
        int p = atomicAdd(&cnt_lds[ld], 1);
        if (p < 64) ell[(ld << 6) + p] = v >> 6;
    }
    __syncthreads();
    int wid = threadIdx.x >> 6, lane = threadIdx.x & 63;
    int sub = lane >> 3, fq = lane & 7;      // 8 sub-groups x 8 lanes (128 B row)
    const H8* Xr = reinterpret_cast<const H8*>(X);   // row = 8 x H8
    for (int ld = wid; ld < 64; ld += 4) {
        int d = (bkt << 6) + ld;
        if (d >= ndst) continue;             // wave-uniform
        int cn = cnt_lds[ld];
        int mm = cn < 64 ? cn : 64;
        float acc[8];
        #pragma unroll
        for (int i = 0; i < 8; ++i) acc[i] = 0.0f;
        for (int e = sub; e < mm; e += 8) {
            int sidx = ell[(ld << 6) + e];
            H8 p = Xr[(size_t)sidx * 8 + fq];
            float2 f0 = __half22float2(p.a);
            float2 f1 = __half22float2(p.b);
            float2 f2 = __half22float2(p.c);
            float2 f3 = __half22float2(p.d);
            acc[0] += f0.x; acc[1] += f0.y; acc[2] += f1.x; acc[3] += f1.y;
            acc[4] += f2.x; acc[5] += f2.y; acc[6] += f3.x; acc[7] += f3.y;
        }
        #pragma unroll
        for (int o = 8; o <= 32; o <<= 1) {
            #pragma unroll
            for (int i = 0; i < 8; ++i) acc[i] += __shfl_xor(acc[i], o, 64);
        }
        if (sub == 0) {
            float inv = (cn > 0) ? (1.0f / (float)cn) : 0.0f;
            H8 o;
            o.a = __floats2half2_rn(acc[0] * inv, acc[1] * inv);
            o.b = __floats2half2_rn(acc[2] * inv, acc[3] * inv);
            o.c = __floats2half2_rn(acc[4] * inv, acc[5] * inv);
            o.d = __floats2half2_rn(acc[6] * inv, acc[7] * inv);
            *reinterpret_cast<H8*>(aggh + (size_t)d * 64 + fq * 8) = o;
        }
    }
}

// ---------------------------------------------------------------------------
// Layer 1 tail, fused: hh = relu((agg1 * hdst1) @ Wout1 + b1)  [in reg/LDS]
// then h_src2 = fp16(hh @ Wsrc2) for all rows; h_dst2 = fp16(hh @ Wdst2)
// for rows < N2. hh never touches global.
__global__ __launch_bounds__(256) void layer1_k(const __half* __restrict__ agg1,
                                                const __half* __restrict__ hdst1,
                                                const __half* __restrict__ wth,
                                                const float* __restrict__ b1,
                                                __half* __restrict__ hsrc2,
                                                __half* __restrict__ hdst2) {
    __shared__ _Float16 zt[4][16][136];      // 16x128 fp16 hh tile, pad->2-way free
    int wave = threadIdx.x >> 6, lane = threadIdx.x & 63;
    int tile = blockIdx.x * 4 + wave;
    if (tile >= NT1) return;
    int r0 = tile * 16;
    int m = lane & 15, q = lane >> 4;
    const _Float16* Az = (const _Float16*)agg1  + (size_t)(r0 + m) * 64 + q * 8;
    const _Float16* Ad = (const _Float16*)hdst1 + (size_t)(r0 + m) * 64 + q * 8;
    const _Float16* wt = (const _Float16*)wth;
    const _Float16* Wout  = wt + 16384;      // [128][64]
    const _Float16* Wsrc2 = wt + 24576;      // [64][128]
    const _Float16* Wdst2 = wt + 32768;      // [64][128]

    // z = agg1 * hdst1 (elementwise, rank-64, A-layout direct from global)
    f32x4 acc2[8];
    #pragma unroll
    for (int nt = 0; nt < 8; ++nt) acc2[nt] = (f32x4)(0.0f);
    #pragma unroll
    for (int kc = 0; kc < 2; ++kc) {
        f16x8 az = *(const f16x8*)(Az + kc * 32);
        f16x8 ad = *(const f16x8*)(Ad + kc * 32);
        f16x8 z;
        #pragma unroll
        for (int i = 0; i < 8; ++i) z[i] = (_Float16)((float)az[i] * (float)ad[i]);
        #pragma unroll
        for (int nt = 0; nt < 8; ++nt) {
            f16x8 bo = *(const f16x8*)(Wout + (nt * 16 + m) * 64 + kc * 32 + q * 8);
            acc2[nt] = MFMA16(z, bo, acc2[nt]);
        }
    }
    // bias + relu -> fp16 hh tile into LDS (C-layout row=q*4+i, col=nt*16+m)
    #pragma unroll
    for (int nt = 0; nt < 8; ++nt) {
        float bz = b1[nt * 16 + m];
        #pragma unroll
        for (int i = 0; i < 4; ++i) {
            float v = fmaxf(acc2[nt][i] + bz, 0.0f);
            zt[wave][q * 4 + i][nt * 16 + m] = (_Float16)v;
        }
    }
    // per-wave LDS ordering: DS ops from one wave complete in order; compiler
    // inserts lgkmcnt for the dependent reads below. No block barrier needed.
    f32x4 accS[4], accD[4];
    #pragma unroll
    for (int nt = 0; nt < 4; ++nt) { accS[nt] = (f32x4)(0.0f); accD[nt] = (f32x4)(0.0f); }
    bool do_dst = (tile < NT2);
    #pragma unroll
    for (int kc = 0; kc < 4; ++kc) {
        f16x8 ah = *(const f16x8*)(&zt[wave][m][kc * 32 + q * 8]);
        #pragma unroll
        for (int nt = 0; nt < 4; ++nt) {
            f16x8 bs = *(const f16x8*)(Wsrc2 + (nt * 16 + m) * 128 + kc * 32 + q * 8);
            accS[nt] = MFMA16(ah, bs, accS[nt]);
        }
        if (do_dst) {
            #pragma unroll
            for (int nt = 0; nt < 4; ++nt) {
                f16x8 bd = *(const f16x8*)(Wdst2 + (nt * 16 + m) * 128 + kc * 32 + q * 8);
                accD[nt] = MFMA16(ah, bd, accD[nt]);
            }
        }
    }
    #pragma unroll
    for (int nt = 0; nt < 4; ++nt)
        #pragma unroll
        for (int i = 0; i < 4; ++i)
            hsrc2[(size_t)(r0 + q * 4 + i) * 64 + nt * 16 + m] = __float2half(accS[nt][i]);
    if (do_dst) {
        #pragma unroll
        for (int nt = 0; nt < 4; ++nt)
            #pragma unroll
            for (int i = 0; i < 4; ++i)
                hdst2[(size_t)(r0 + q * 4 + i) * 64 + nt * 16 + m] = __float2half(accD[nt][i]);
    }
}

// ---------------------------------------------------------------------------
// Layer 2 tail: out = (agg2 * hdst2) @ Wout2 + b2. No LDS.
__global__ __launch_bounds__(256) void layer2_k(const __half* __restrict__ agg2,
                                                const __half* __restrict__ hdst2,
                                                const __half* __restrict__ wth,
                                                const float* __restrict__ b2,
                                                float* __restrict__ out) {
    int wave = threadIdx.x >> 6, lane = threadIdx.x & 63;
    int tile = blockIdx.x * 4 + wave;
    if (tile >= NT2) return;
    int r0 = tile * 16;
    int m = lane & 15, q = lane >> 4;
    const _Float16* Az = (const _Float16*)agg2  + (size_t)(r0 + m) * 64 + q * 8;
    const _Float16* Ad = (const _Float16*)hdst2 + (size_t)(r0 + m) * 64 + q * 8;
    const _Float16* Wout = (const _Float16*)wth + 40960;   // [64][64]

    f32x4 acc[4];
    #pragma unroll
    for (int nt = 0; nt < 4; ++nt) acc[nt] = (f32x4)(0.0f);
    #pragma unroll
    for (int kc = 0; kc < 2; ++kc) {
        f16x8 az = *(const f16x8*)(Az + kc * 32);
        f16x8 ad = *(const f16x8*)(Ad + kc * 32);
        f16x8 z;
        #pragma unroll
        for (int i = 0; i < 8; ++i) z[i] = (_Float16)((float)az[i] * (float)ad[i]);
        #pragma unroll
        for (int nt = 0; nt < 4; ++nt) {
            f16x8 bo = *(const f16x8*)(Wout + (nt * 16 + m) * 64 + kc * 32 + q * 8);
            acc[nt] = MFMA16(z, bo, acc[nt]);
        }
    }
    #pragma unroll
    for (int nt = 0; nt < 4; ++nt) {
        float bz = b2[nt * 16 + m];
        #pragma unroll
        for (int i = 0; i < 4; ++i)
            out[(size_t)(r0 + q * 4 + i) * 64 + nt * 16 + m] = acc[nt][i] + bz;
    }
}

// ---------------------------------------------------------------------------
extern "C" void kernel_launch(void* const* d_in, const int* in_sizes, int n_in,
                              void* d_out, int out_size, void* d_ws, size_t ws_size,
                              hipStream_t stream) {
    const float* x     = (const float*)d_in[0];
    const float* Wsrc1 = (const float*)d_in[1];
    const float* Wdst1 = (const float*)d_in[2];
    const float* Wout1 = (const float*)d_in[3];
    const float* b1    = (const float*)d_in[4];
    const float* Wsrc2 = (const float*)d_in[5];
    const float* Wdst2 = (const float*)d_in[6];
    const float* Wout2 = (const float*)d_in[7];
    const float* b2    = (const float*)d_in[8];
    const int* src1    = (const int*)d_in[9];
    const int* dst1    = (const int*)d_in[10];
    const int* src2    = (const int*)d_in[11];
    const int* dst2    = (const int*)d_in[12];
    float* out = (float*)d_out;

    // workspace layout (byte offsets, all 16B-aligned)
    char* basep = (char*)d_ws;
    __half* hsrc1 = (__half*)(basep);                  // 25.6 MB [N0][64]
    __half* hdst1 = (__half*)(basep + 25600000);       //  6.4 MB [N1][64]
    __half* agg1  = (__half*)(basep + 32000000);       //  6.4 MB [N1][64]
    __half* hsrc2 = (__half*)(basep + 38400000);       //  6.4 MB [N1][64]
    __half* hdst2 = (__half*)(basep + 44800000);       // 1.28 MB [N2][64]
    __half* agg2  = (__half*)(basep + 46080000);       // 1.28 MB [N2][64]
    int* hist    = (int*)(basep + 47360000);           // NBT
    int* bbase   = hist + NBT;
    int* cursor  = bbase + NBT;
    int* edgebuf = (int*)(basep + 47371328);           // 960000 ints
    __half* wt   = (__half*)(basep + 51211328);        // 90 KB transposed weights

    // --- tiny prep (zero hist + W->fp16 transposed) ---
    {
        int total = NBT / 4 + WT_TOTAL;
        prep_small<<<(total + 255) / 256, 256, 0, stream>>>((int4*)hist,
                                                            Wsrc1, Wdst1, Wout1, Wsrc2, Wdst2, Wout2, wt);
    }
    // --- bucket histogram -> scan -> coalesced bucket scatter ---
    hist_k<<<CH1 + CH2, 256, 0, stream>>>(dst1, dst2, hist);
    scan_small<<<1, 1024, 0, stream>>>(hist, bbase, cursor);
    scatter_k<<<8 * CH1 + 8 * CH2, 256, 0, stream>>>(dst1, src1, dst2, src2, cursor, edgebuf);

    // --- projection (rank space), then layer 1 ---
    proj1<<<(NTP + 3) / 4, 256, 0, stream>>>(x, wt, hsrc1, hdst1);
    seg_mean64<<<782, 256, 0, stream>>>(hsrc1, edgebuf, bbase, hist, agg1, N1, 0);
    layer1_k<<<(NT1 + 3) / 4, 256, 0, stream>>>(agg1, hdst1, wt, b1, hsrc2, hdst2);

    // --- layer 2 ---
    seg_mean64<<<157, 256, 0, stream>>>(hsrc2, edgebuf, bbase, hist, agg2, N2, NB1);
    layer2_k<<<(NT2 + 3) / 4, 256, 0, stream>>>(agg2, hdst2, wt, b2, out);
}